// Round 5
// baseline (266.258 us; speedup 1.0000x reference)
//
#include <hip/hip_runtime.h>

typedef __bf16 bf16;
typedef __bf16 bf16x8 __attribute__((ext_vector_type(8)));
typedef __bf16 bf16x4 __attribute__((ext_vector_type(4)));
typedef __bf16 bf16x2 __attribute__((ext_vector_type(2)));
typedef float f32x4 __attribute__((ext_vector_type(4)));

#define MM 4096   // B*S
#define NN 1024   // E
#define KK 1024   // E

__device__ __forceinline__ void gload_lds16(const void* g, void* l) {
  __builtin_amdgcn_global_load_lds(
      (const __attribute__((address_space(1))) void*)g,
      (__attribute__((address_space(3))) void*)l, 16, 0, 0);
}

// ---------------- fused converts: activations + weights -> bf16 ----------------
__global__ __launch_bounds__(256) void cvt_all(const float* __restrict__ q,
                                               const float* __restrict__ k,
                                               const float* __restrict__ v,
                                               const float* __restrict__ Wq,
                                               const float* __restrict__ Wk,
                                               const float* __restrict__ Wv,
                                               const float* __restrict__ Wo,
                                               bf16* __restrict__ Xb,
                                               bf16* __restrict__ Wt,
                                               bf16* __restrict__ Wot)
{
  __shared__ bf16 Sl[64 * 72];
  const int bid = blockIdx.x;
  const int t = threadIdx.x;

  if (bid < 12288) {
    int p = bid >> 12, bx = bid & 4095;
    const float* src = (p == 0) ? q : (p == 1 ? k : v);
    bf16* dst = Xb + (size_t)p * (MM * (size_t)KK);
    int i = (bx * 256 + t) * 4;
    float4 val = *(const float4*)(src + i);
    bf16x4 o;
    o.x = (bf16)val.x; o.y = (bf16)val.y; o.z = (bf16)val.z; o.w = (bf16)val.w;
    *(bf16x4*)(dst + i) = o;
    return;
  }

  const int wb = bid - 12288;          // 0..1023
  const int p = wb >> 8, t8 = wb & 255;
  const int ti = t >> 4, c4 = (t & 15) * 4;

  if (p < 3) {
    const float* W = (p == 0) ? Wq : (p == 1 ? Wk : Wv);
    const int h = t8 >> 4, e0 = (t8 & 15) << 6;
#pragma unroll
    for (int r = 0; r < 4; ++r) {
      int e_l = r * 16 + ti;
      float4 val = *(const float4*)(W + (h << 16) + (e0 + e_l) * 64 + c4);
      bf16x4 o; o.x = (bf16)val.x; o.y = (bf16)val.y; o.z = (bf16)val.z; o.w = (bf16)val.w;
      *(bf16x4*)(Sl + e_l * 72 + c4) = o;
    }
    __syncthreads();
#pragma unroll
    for (int r = 0; r < 4; ++r) {
      int d_l = r * 16 + ti;
      bf16x4 o;
      o.x = Sl[(c4 + 0) * 72 + d_l];
      o.y = Sl[(c4 + 1) * 72 + d_l];
      o.z = Sl[(c4 + 2) * 72 + d_l];
      o.w = Sl[(c4 + 3) * 72 + d_l];
      *(bf16x4*)(Wt + (size_t)p * 1048576 + (size_t)((h << 6) + d_l) * 1024 + e0 + c4) = o;
    }
  } else {
    const int n0 = (t8 >> 4) << 6, k0 = (t8 & 15) << 6;
#pragma unroll
    for (int r = 0; r < 4; ++r) {
      int k_l = r * 16 + ti;
      float4 val = *(const float4*)(Wo + (size_t)(k0 + k_l) * 1024 + n0 + c4);
      bf16x4 o; o.x = (bf16)val.x; o.y = (bf16)val.y; o.z = (bf16)val.z; o.w = (bf16)val.w;
      *(bf16x4*)(Sl + k_l * 72 + c4) = o;
    }
    __syncthreads();
#pragma unroll
    for (int r = 0; r < 4; ++r) {
      int n_l = r * 16 + ti;
      bf16x4 o;
      o.x = Sl[(c4 + 0) * 72 + n_l];
      o.y = Sl[(c4 + 1) * 72 + n_l];
      o.z = Sl[(c4 + 2) * 72 + n_l];
      o.w = Sl[(c4 + 3) * 72 + n_l];
      *(bf16x4*)(Wot + (size_t)(n0 + n_l) * 1024 + k0 + c4) = o;
    }
  }
}

// ---------------- m97-style 128x128 bf16 GEMM core ----------------
__device__ __forceinline__ void gemm_body(const bf16* __restrict__ A,
                                          const bf16* __restrict__ Bt,
                                          bf16* As, bf16* Bs,
                                          int m0, int n0, f32x4 (&acc)[4][4])
{
  const int tid = threadIdx.x;
  const int w = tid >> 6, L = tid & 63;
  const int quad = L >> 4, l16 = L & 15;
  const int wm = (w & 1) << 6, wn = (w >> 1) << 6;

  const bf16* Ag = A + (size_t)(m0 + w * 32 + (L >> 2)) * KK + (L & 3) * 8;
  const bf16* Bg = Bt + (size_t)(n0 + w * 32 + (L >> 2)) * KK + (L & 3) * 8;
  bf16* Al = As + w * 1024;
  bf16* Bl = Bs + w * 1024;

  for (int kt = 0; kt < KK / 32; ++kt) {
    __syncthreads();
    const bf16* a0 = Ag + kt * 32;
    const bf16* b0 = Bg + kt * 32;
    gload_lds16(a0, Al);
    gload_lds16(a0 + 16 * KK, Al + 512);
    gload_lds16(b0, Bl);
    gload_lds16(b0 + 16 * KK, Bl + 512);
    __syncthreads();
    bf16x8 af[4], bfr[4];
#pragma unroll
    for (int mi = 0; mi < 4; ++mi)
      af[mi] = *(const bf16x8*)(As + (wm + mi * 16 + l16) * 32 + quad * 8);
#pragma unroll
    for (int ni = 0; ni < 4; ++ni)
      bfr[ni] = *(const bf16x8*)(Bs + (wn + ni * 16 + l16) * 32 + quad * 8);
#pragma unroll
    for (int mi = 0; mi < 4; ++mi)
#pragma unroll
      for (int ni = 0; ni < 4; ++ni)
        acc[mi][ni] = __builtin_amdgcn_mfma_f32_16x16x32_bf16(af[mi], bfr[ni],
                                                              acc[mi][ni], 0, 0, 0);
  }
}

// fused Q/K projections + V^T projection. 768 blocks.
__global__ __launch_bounds__(256) void gemm_qkvt(const bf16* __restrict__ Xb,
                                                 const bf16* __restrict__ Wt,
                                                 const float* __restrict__ bq,
                                                 const float* __restrict__ bk,
                                                 const float* __restrict__ bv,
                                                 bf16* __restrict__ QK,
                                                 bf16* __restrict__ VtOut)
{
  __shared__ bf16 As[4096], Bs[4096];
  const int bid = blockIdx.x;
  const int L = threadIdx.x & 63, w = threadIdx.x >> 6;
  const int quad = L >> 4, l16 = L & 15;
  const int wm = (w & 1) << 6, wn = (w >> 1) << 6;
  f32x4 acc[4][4] = {};

  if (bid < 512) {
    const int p = bid >> 8, t8 = bid & 255;
    const int m0 = (t8 >> 3) << 7, n0 = (t8 & 7) << 7;
    gemm_body(Xb + (size_t)p * 4194304, Wt + (size_t)p * 1048576, As, Bs, m0, n0, acc);
    const float* bias = p ? bk : bq;
    bf16* C = QK + (size_t)p * 4194304;
#pragma unroll
    for (int ni = 0; ni < 4; ++ni) {
      int col = n0 + wn + ni * 16 + l16;
      float bvv = bias[col];
#pragma unroll
      for (int mi = 0; mi < 4; ++mi)
#pragma unroll
        for (int r = 0; r < 4; ++r) {
          int row = m0 + wm + mi * 16 + quad * 4 + r;
          C[(size_t)row * NN + col] = (bf16)(acc[mi][ni][r] + bvv);
        }
    }
  } else {
    const int t8 = bid - 512;
    const int m0 = (t8 >> 5) << 7, n0 = (t8 & 31) << 7;   // M=1024 (h,d), N=4096 (b,s)
    gemm_body(Wt + 2 * 1048576, Xb + 2 * 4194304, As, Bs, m0, n0, acc);
#pragma unroll
    for (int ni = 0; ni < 4; ++ni) {
      int n = n0 + wn + ni * 16 + l16;
      int bb = n >> 11, sl = n & 2047;
#pragma unroll
      for (int mi = 0; mi < 4; ++mi)
#pragma unroll
        for (int r = 0; r < 4; ++r) {
          int m = m0 + wm + mi * 16 + quad * 4 + r;
          VtOut[(size_t)((bb << 4) + (m >> 6)) * 131072 + (m & 63) * 2048 + sl]
              = (bf16)(acc[mi][ni][r] + bv[m]);
        }
    }
  }
}

// ---------------- 64x128-tile GEMM for the output projection ----------------
__global__ __launch_bounds__(256) void gemm_outp(const bf16* __restrict__ A,
                                                 const bf16* __restrict__ Bt,
                                                 const float* __restrict__ bias,
                                                 float* __restrict__ C)
{
  __shared__ bf16 As[2048], Bs[4096];
  const int bx = blockIdx.x;
  const int m0 = (bx >> 3) << 6, n0 = (bx & 7) << 7;
  const int tid = threadIdx.x;
  const int w = tid >> 6, L = tid & 63;
  const int quad = L >> 4, l16 = L & 15;
  const int wm = (w & 1) << 5, wn = (w >> 1) << 6;

  const bf16* Ag = A + (size_t)(m0 + w * 16 + (L >> 2)) * KK + (L & 3) * 8;
  const bf16* Bg = Bt + (size_t)(n0 + w * 32 + (L >> 2)) * KK + (L & 3) * 8;
  bf16* Al = As + w * 512;
  bf16* Bl = Bs + w * 1024;

  f32x4 acc[2][4] = {};
  for (int kt = 0; kt < KK / 32; ++kt) {
    __syncthreads();
    const bf16* a0 = Ag + kt * 32;
    const bf16* b0 = Bg + kt * 32;
    gload_lds16(a0, Al);
    gload_lds16(b0, Bl);
    gload_lds16(b0 + 16 * KK, Bl + 512);
    __syncthreads();
    bf16x8 af[2], bfr[4];
#pragma unroll
    for (int mi = 0; mi < 2; ++mi)
      af[mi] = *(const bf16x8*)(As + (wm + mi * 16 + l16) * 32 + quad * 8);
#pragma unroll
    for (int ni = 0; ni < 4; ++ni)
      bfr[ni] = *(const bf16x8*)(Bs + (wn + ni * 16 + l16) * 32 + quad * 8);
#pragma unroll
    for (int mi = 0; mi < 2; ++mi)
#pragma unroll
      for (int ni = 0; ni < 4; ++ni)
        acc[mi][ni] = __builtin_amdgcn_mfma_f32_16x16x32_bf16(af[mi], bfr[ni],
                                                              acc[mi][ni], 0, 0, 0);
  }

#pragma unroll
  for (int ni = 0; ni < 4; ++ni) {
    int col = n0 + wn + ni * 16 + l16;
    float bv = bias[col];
#pragma unroll
    for (int mi = 0; mi < 2; ++mi)
#pragma unroll
      for (int r = 0; r < 4; ++r) {
        int row = m0 + wm + mi * 16 + quad * 4 + r;
        C[(size_t)row * NN + col] = acc[mi][ni][r] + bv;
      }
  }
}

// ---------------- flash attention v5: key-split waves, prefetch, slim LDS ----
// blockIdx = qb*32 + bh  (XCD swizzle: all 32 q-blocks of a head -> XCD bh%8).
// Wave w owns keys [w*512,(w+1)*512) for all 64 q-rows; 16 t-iters x 32 keys.
// K,V^T global->register with one-tile prefetch. No barriers in main loop
// (P transpose is wave-private LDS). l folded into a ones-vector MFMA.
// Tail: serial 5-barrier cross-wave O reduce through one 16KB buffer.
__global__ __launch_bounds__(256) void flash_attn(const bf16* __restrict__ Qm,
                                                  const bf16* __restrict__ Km,
                                                  const bf16* __restrict__ Vt,
                                                  bf16* __restrict__ Om)
{
  __shared__ bf16 Pl[4][64 * 40];   // 20 KB, per-wave P transpose
  __shared__ f32x4 Obuf[1024];      // 16 KB, serial cross-wave reduce
  __shared__ float Lred[4][64];     // 1 KB

  const int tid = threadIdx.x;
  const int w = tid >> 6, L = tid & 63;
  const int quad = L >> 4, l16 = L & 15;
  const int bh = blockIdx.x & 31;
  const int qb = blockIdx.x >> 5;
  const int b = bh >> 4, h = bh & 15;
  const int s0 = qb << 6;
  const size_t baseQ = (size_t)b * 2097152 + h * 64;
  const size_t baseV = (size_t)bh * 131072;

  // Q fragments (4 m-tiles x 2 dh-halves), scale*log2e folded in
  bf16x8 qf[4][2];
  const float SL = 0.03125f * 1.44269504088896f;
  {
    const bf16* qp = Qm + baseQ + (size_t)(s0 + l16) * 1024 + quad * 8;
#pragma unroll
    for (int mi = 0; mi < 4; ++mi)
#pragma unroll
      for (int h2 = 0; h2 < 2; ++h2) {
        bf16x8 tq = *(const bf16x8*)(qp + mi * 16384 + h2 * 32);
#pragma unroll
        for (int j = 0; j < 8; ++j) tq[j] = (bf16)((float)tq[j] * SL);
        qf[mi][h2] = tq;
      }
  }

  bf16x8 onesf;
#pragma unroll
  for (int j = 0; j < 8; ++j) onesf[j] = (bf16)1.0f;

  f32x4 oacc[4][4] = {};
  f32x4 lacc[4] = {};

  // K rows interleaved: P col (2*l16+kt2) = key index within the 32-key step
  const bf16* Kg = Km + baseQ + (size_t)(w * 512 + 2 * l16) * 1024 + quad * 8;
  const bf16* Vg = Vt + baseV + (size_t)l16 * 2048 + w * 512 + quad * 8;
  bf16* Pw = &Pl[w][0];

  bf16x8 kc[2][2], vc[4];
#pragma unroll
  for (int kt2 = 0; kt2 < 2; ++kt2)
#pragma unroll
    for (int h2 = 0; h2 < 2; ++h2)
      kc[kt2][h2] = *(const bf16x8*)(Kg + kt2 * 1024 + h2 * 32);
#pragma unroll
  for (int ds = 0; ds < 4; ++ds)
    vc[ds] = *(const bf16x8*)(Vg + ds * 32768);

  for (int t = 0; t < 16; ++t) {
    // prefetch t+1 (flight overlaps with this iter's compute)
    bf16x8 kn[2][2], vn[4];
    if (t + 1 < 16) {
      const bf16* kg = Kg + (size_t)(t + 1) * 32768;
      const bf16* vg = Vg + (t + 1) * 32;
#pragma unroll
      for (int kt2 = 0; kt2 < 2; ++kt2)
#pragma unroll
        for (int h2 = 0; h2 < 2; ++h2)
          kn[kt2][h2] = *(const bf16x8*)(kg + kt2 * 1024 + h2 * 32);
#pragma unroll
      for (int ds = 0; ds < 4; ++ds)
        vn[ds] = *(const bf16x8*)(vg + ds * 32768);
    }

    // S = Q K^T, exp2, packed P store (col = 2*l16+kt2, conflict-free b32)
#pragma unroll
    for (int mi = 0; mi < 4; ++mi) {
      f32x4 sa = {0.f, 0.f, 0.f, 0.f}, sb = {0.f, 0.f, 0.f, 0.f};
      sa = __builtin_amdgcn_mfma_f32_16x16x32_bf16(qf[mi][0], kc[0][0], sa, 0, 0, 0);
      sa = __builtin_amdgcn_mfma_f32_16x16x32_bf16(qf[mi][1], kc[0][1], sa, 0, 0, 0);
      sb = __builtin_amdgcn_mfma_f32_16x16x32_bf16(qf[mi][0], kc[1][0], sb, 0, 0, 0);
      sb = __builtin_amdgcn_mfma_f32_16x16x32_bf16(qf[mi][1], kc[1][1], sb, 0, 0, 0);
#pragma unroll
      for (int r = 0; r < 4; ++r) {
        float p0 = __builtin_amdgcn_exp2f(sa[r]);
        float p1 = __builtin_amdgcn_exp2f(sb[r]);
        bf16x2 pv; pv.x = (bf16)p0; pv.y = (bf16)p1;
        *(bf16x2*)(Pw + (mi * 16 + quad * 4 + r) * 40 + 2 * l16) = pv;
      }
    }
    asm volatile("s_waitcnt lgkmcnt(0)" ::: "memory");  // Pl is wave-local

    // O += P V^T; l += P * ones  (P: A-frag from LDS, conflict-optimal b128)
#pragma unroll
    for (int mi = 0; mi < 4; ++mi) {
      bf16x8 paf = *(const bf16x8*)(Pw + (mi * 16 + l16) * 40 + quad * 8);
#pragma unroll
      for (int ds = 0; ds < 4; ++ds)
        oacc[mi][ds] = __builtin_amdgcn_mfma_f32_16x16x32_bf16(paf, vc[ds],
                                                               oacc[mi][ds], 0, 0, 0);
      lacc[mi] = __builtin_amdgcn_mfma_f32_16x16x32_bf16(paf, onesf, lacc[mi], 0, 0, 0);
    }

#pragma unroll
    for (int kt2 = 0; kt2 < 2; ++kt2)
#pragma unroll
      for (int h2 = 0; h2 < 2; ++h2)
        kc[kt2][h2] = kn[kt2][h2];
#pragma unroll
    for (int ds = 0; ds < 4; ++ds)
      vc[ds] = vn[ds];
  }

  // ---- tail: publish l; serial cross-wave O reduce via 16 KB buffer ----
  if (l16 == 0) {
#pragma unroll
    for (int mi = 0; mi < 4; ++mi)
#pragma unroll
      for (int r = 0; r < 4; ++r)
        Lred[w][mi * 16 + quad * 4 + r] = lacc[mi][r];
  }

  if (w == 1) {
#pragma unroll
    for (int mi = 0; mi < 4; ++mi)
#pragma unroll
      for (int ds = 0; ds < 4; ++ds)
        Obuf[(mi * 4 + ds) * 64 + L] = oacc[mi][ds];
  }
  __syncthreads();
  if (w == 0) {
#pragma unroll
    for (int mi = 0; mi < 4; ++mi)
#pragma unroll
      for (int ds = 0; ds < 4; ++ds)
        oacc[mi][ds] += Obuf[(mi * 4 + ds) * 64 + L];
  }
  __syncthreads();
  if (w == 2) {
#pragma unroll
    for (int mi = 0; mi < 4; ++mi)
#pragma unroll
      for (int ds = 0; ds < 4; ++ds)
        Obuf[(mi * 4 + ds) * 64 + L] = oacc[mi][ds];
  }
  __syncthreads();
  if (w == 0) {
#pragma unroll
    for (int mi = 0; mi < 4; ++mi)
#pragma unroll
      for (int ds = 0; ds < 4; ++ds)
        oacc[mi][ds] += Obuf[(mi * 4 + ds) * 64 + L];
  }
  __syncthreads();
  if (w == 3) {
#pragma unroll
    for (int mi = 0; mi < 4; ++mi)
#pragma unroll
      for (int ds = 0; ds < 4; ++ds)
        Obuf[(mi * 4 + ds) * 64 + L] = oacc[mi][ds];
  }
  __syncthreads();
  if (w == 0) {
#pragma unroll
    for (int mi = 0; mi < 4; ++mi) {
#pragma unroll
      for (int ds = 0; ds < 4; ++ds)
        oacc[mi][ds] += Obuf[(mi * 4 + ds) * 64 + L];
#pragma unroll
      for (int r = 0; r < 4; ++r) {
        int qr = mi * 16 + quad * 4 + r;
        float lt = Lred[0][qr] + Lred[1][qr] + Lred[2][qr] + Lred[3][qr];
        float inv = 1.f / lt;
        bf16* op = Om + baseQ + (size_t)(s0 + qr) * 1024;
#pragma unroll
        for (int ds = 0; ds < 4; ++ds)
          op[ds * 16 + l16] = (bf16)(oacc[mi][ds][r] * inv);
      }
    }
  }
}

extern "C" void kernel_launch(void* const* d_in, const int* in_sizes, int n_in,
                              void* d_out, int out_size, void* d_ws, size_t ws_size,
                              hipStream_t stream)
{
  const float* q  = (const float*)d_in[0];
  const float* k  = (const float*)d_in[1];
  const float* v  = (const float*)d_in[2];
  const float* Wq = (const float*)d_in[3];
  const float* bq = (const float*)d_in[4];
  const float* Wk = (const float*)d_in[5];
  const float* bk = (const float*)d_in[6];
  const float* Wv = (const float*)d_in[7];
  const float* bv = (const float*)d_in[8];
  const float* Wo = (const float*)d_in[9];
  const float* bo = (const float*)d_in[10];

  char* ws = (char*)d_ws;
  bf16* Xb  = (bf16*)ws;                    // 3 x 4096x1024 bf16 (dead after gemm_qkvt)
  bf16* Wt  = (bf16*)(ws + 25165824);       // 3 x 1024x1024 bf16
  bf16* Wot = (bf16*)(ws + 31457280);       // 1024x1024 bf16
  bf16* QK  = (bf16*)(ws + 33554432);       // 2 x 4096x1024 bf16 (Q,K)
  bf16* Vtg = (bf16*)(ws + 50331648);       // [bh][64][2048] bf16 (V^T)
  bf16* O   = (bf16*)ws;                    // aliases Xb

  cvt_all<<<dim3(13312), 256, 0, stream>>>(q, k, v, Wq, Wk, Wv, Wo, Xb, Wt, Wot);
  gemm_qkvt<<<dim3(768), 256, 0, stream>>>(Xb, Wt, bq, bk, bv, QK, Vtg);
  flash_attn<<<dim3(1024), 256, 0, stream>>>(QK, QK + 4194304, Vtg, O);
  gemm_outp<<<dim3(512), 256, 0, stream>>>(O, Wot, bo, (float*)d_out);
}

// Round 6
// 229.729 us; speedup vs baseline: 1.1590x; 1.1590x over previous
//
#include <hip/hip_runtime.h>

typedef __bf16 bf16;
typedef __bf16 bf16x8 __attribute__((ext_vector_type(8)));
typedef __bf16 bf16x4 __attribute__((ext_vector_type(4)));
typedef __bf16 bf16x2 __attribute__((ext_vector_type(2)));
typedef float f32x4 __attribute__((ext_vector_type(4)));
typedef float f32x16 __attribute__((ext_vector_type(16)));

#define MM 4096   // B*S
#define NN 1024   // E
#define KK 1024   // E

__device__ __forceinline__ void gload_lds16(const void* g, void* l) {
  __builtin_amdgcn_global_load_lds(
      (const __attribute__((address_space(1))) void*)g,
      (__attribute__((address_space(3))) void*)l, 16, 0, 0);
}

// ---------------- fused converts: activations + weights -> bf16 ----------------
__global__ __launch_bounds__(256) void cvt_all(const float* __restrict__ q,
                                               const float* __restrict__ k,
                                               const float* __restrict__ v,
                                               const float* __restrict__ Wq,
                                               const float* __restrict__ Wk,
                                               const float* __restrict__ Wv,
                                               const float* __restrict__ Wo,
                                               bf16* __restrict__ Xb,
                                               bf16* __restrict__ Wt,
                                               bf16* __restrict__ Wot)
{
  __shared__ bf16 Sl[64 * 72];
  const int bid = blockIdx.x;
  const int t = threadIdx.x;

  if (bid < 12288) {
    int p = bid >> 12, bx = bid & 4095;
    const float* src = (p == 0) ? q : (p == 1 ? k : v);
    bf16* dst = Xb + (size_t)p * (MM * (size_t)KK);
    int i = (bx * 256 + t) * 4;
    float4 val = *(const float4*)(src + i);
    bf16x4 o;
    o.x = (bf16)val.x; o.y = (bf16)val.y; o.z = (bf16)val.z; o.w = (bf16)val.w;
    *(bf16x4*)(dst + i) = o;
    return;
  }

  const int wb = bid - 12288;          // 0..1023
  const int p = wb >> 8, t8 = wb & 255;
  const int ti = t >> 4, c4 = (t & 15) * 4;

  if (p < 3) {
    const float* W = (p == 0) ? Wq : (p == 1 ? Wk : Wv);
    const int h = t8 >> 4, e0 = (t8 & 15) << 6;
#pragma unroll
    for (int r = 0; r < 4; ++r) {
      int e_l = r * 16 + ti;
      float4 val = *(const float4*)(W + (h << 16) + (e0 + e_l) * 64 + c4);
      bf16x4 o; o.x = (bf16)val.x; o.y = (bf16)val.y; o.z = (bf16)val.z; o.w = (bf16)val.w;
      *(bf16x4*)(Sl + e_l * 72 + c4) = o;
    }
    __syncthreads();
#pragma unroll
    for (int r = 0; r < 4; ++r) {
      int d_l = r * 16 + ti;
      bf16x4 o;
      o.x = Sl[(c4 + 0) * 72 + d_l];
      o.y = Sl[(c4 + 1) * 72 + d_l];
      o.z = Sl[(c4 + 2) * 72 + d_l];
      o.w = Sl[(c4 + 3) * 72 + d_l];
      *(bf16x4*)(Wt + (size_t)p * 1048576 + (size_t)((h << 6) + d_l) * 1024 + e0 + c4) = o;
    }
  } else {
    const int n0 = (t8 >> 4) << 6, k0 = (t8 & 15) << 6;
#pragma unroll
    for (int r = 0; r < 4; ++r) {
      int k_l = r * 16 + ti;
      float4 val = *(const float4*)(Wo + (size_t)(k0 + k_l) * 1024 + n0 + c4);
      bf16x4 o; o.x = (bf16)val.x; o.y = (bf16)val.y; o.z = (bf16)val.z; o.w = (bf16)val.w;
      *(bf16x4*)(Sl + k_l * 72 + c4) = o;
    }
    __syncthreads();
#pragma unroll
    for (int r = 0; r < 4; ++r) {
      int n_l = r * 16 + ti;
      bf16x4 o;
      o.x = Sl[(c4 + 0) * 72 + n_l];
      o.y = Sl[(c4 + 1) * 72 + n_l];
      o.z = Sl[(c4 + 2) * 72 + n_l];
      o.w = Sl[(c4 + 3) * 72 + n_l];
      *(bf16x4*)(Wot + (size_t)(n0 + n_l) * 1024 + k0 + c4) = o;
    }
  }
}

// ---------------- m97-style 128x128 bf16 GEMM core ----------------
__device__ __forceinline__ void gemm_body(const bf16* __restrict__ A,
                                          const bf16* __restrict__ Bt,
                                          bf16* As, bf16* Bs,
                                          int m0, int n0, f32x4 (&acc)[4][4])
{
  const int tid = threadIdx.x;
  const int w = tid >> 6, L = tid & 63;
  const int quad = L >> 4, l16 = L & 15;
  const int wm = (w & 1) << 6, wn = (w >> 1) << 6;

  const bf16* Ag = A + (size_t)(m0 + w * 32 + (L >> 2)) * KK + (L & 3) * 8;
  const bf16* Bg = Bt + (size_t)(n0 + w * 32 + (L >> 2)) * KK + (L & 3) * 8;
  bf16* Al = As + w * 1024;
  bf16* Bl = Bs + w * 1024;

  for (int kt = 0; kt < KK / 32; ++kt) {
    __syncthreads();
    const bf16* a0 = Ag + kt * 32;
    const bf16* b0 = Bg + kt * 32;
    gload_lds16(a0, Al);
    gload_lds16(a0 + 16 * KK, Al + 512);
    gload_lds16(b0, Bl);
    gload_lds16(b0 + 16 * KK, Bl + 512);
    __syncthreads();
    bf16x8 af[4], bfr[4];
#pragma unroll
    for (int mi = 0; mi < 4; ++mi)
      af[mi] = *(const bf16x8*)(As + (wm + mi * 16 + l16) * 32 + quad * 8);
#pragma unroll
    for (int ni = 0; ni < 4; ++ni)
      bfr[ni] = *(const bf16x8*)(Bs + (wn + ni * 16 + l16) * 32 + quad * 8);
#pragma unroll
    for (int mi = 0; mi < 4; ++mi)
#pragma unroll
      for (int ni = 0; ni < 4; ++ni)
        acc[mi][ni] = __builtin_amdgcn_mfma_f32_16x16x32_bf16(af[mi], bfr[ni],
                                                              acc[mi][ni], 0, 0, 0);
  }
}

__global__ __launch_bounds__(256) void gemm_proj(const bf16* __restrict__ X,
                                                 const bf16* __restrict__ Wt,
                                                 const float* __restrict__ b0,
                                                 const float* __restrict__ b1,
                                                 const float* __restrict__ b2,
                                                 bf16* __restrict__ Out)
{
  __shared__ bf16 As[4096], Bs[4096];
  int p = blockIdx.y;
  const bf16* A = X + (size_t)p * 4194304;
  const bf16* Bt = Wt + (size_t)p * 1048576;
  const float* bias = (p == 0) ? b0 : (p == 1 ? b1 : b2);
  bf16* C = Out + (size_t)p * 4194304;
  int bx = blockIdx.x;
  int m0 = (bx >> 3) << 7, n0 = (bx & 7) << 7;
  f32x4 acc[4][4] = {};
  gemm_body(A, Bt, As, Bs, m0, n0, acc);
  const int L = threadIdx.x & 63, w = threadIdx.x >> 6;
  const int quad = L >> 4, l16 = L & 15;
  const int wm = (w & 1) << 6, wn = (w >> 1) << 6;
#pragma unroll
  for (int ni = 0; ni < 4; ++ni) {
    int col = n0 + wn + ni * 16 + l16;
    float bv = bias[col];
#pragma unroll
    for (int mi = 0; mi < 4; ++mi)
#pragma unroll
      for (int r = 0; r < 4; ++r) {
        int row = m0 + wm + mi * 16 + quad * 4 + r;
        C[(size_t)row * NN + col] = (bf16)(acc[mi][ni][r] + bv);
      }
  }
}

// ---------------- 64x128-tile GEMM for the output projection ----------------
__global__ __launch_bounds__(256) void gemm_outp(const bf16* __restrict__ A,
                                                 const bf16* __restrict__ Bt,
                                                 const float* __restrict__ bias,
                                                 float* __restrict__ C)
{
  __shared__ bf16 As[2048], Bs[4096];
  const int bx = blockIdx.x;
  const int m0 = (bx >> 3) << 6, n0 = (bx & 7) << 7;
  const int tid = threadIdx.x;
  const int w = tid >> 6, L = tid & 63;
  const int quad = L >> 4, l16 = L & 15;
  const int wm = (w & 1) << 5, wn = (w >> 1) << 6;

  const bf16* Ag = A + (size_t)(m0 + w * 16 + (L >> 2)) * KK + (L & 3) * 8;
  const bf16* Bg = Bt + (size_t)(n0 + w * 32 + (L >> 2)) * KK + (L & 3) * 8;
  bf16* Al = As + w * 512;
  bf16* Bl = Bs + w * 1024;

  f32x4 acc[2][4] = {};
  for (int kt = 0; kt < KK / 32; ++kt) {
    __syncthreads();
    const bf16* a0 = Ag + kt * 32;
    const bf16* b0 = Bg + kt * 32;
    gload_lds16(a0, Al);
    gload_lds16(b0, Bl);
    gload_lds16(b0 + 16 * KK, Bl + 512);
    __syncthreads();
    bf16x8 af[2], bfr[4];
#pragma unroll
    for (int mi = 0; mi < 2; ++mi)
      af[mi] = *(const bf16x8*)(As + (wm + mi * 16 + l16) * 32 + quad * 8);
#pragma unroll
    for (int ni = 0; ni < 4; ++ni)
      bfr[ni] = *(const bf16x8*)(Bs + (wn + ni * 16 + l16) * 32 + quad * 8);
#pragma unroll
    for (int mi = 0; mi < 2; ++mi)
#pragma unroll
      for (int ni = 0; ni < 4; ++ni)
        acc[mi][ni] = __builtin_amdgcn_mfma_f32_16x16x32_bf16(af[mi], bfr[ni],
                                                              acc[mi][ni], 0, 0, 0);
  }

#pragma unroll
  for (int ni = 0; ni < 4; ++ni) {
    int col = n0 + wn + ni * 16 + l16;
    float bv = bias[col];
#pragma unroll
    for (int mi = 0; mi < 2; ++mi)
#pragma unroll
      for (int r = 0; r < 4; ++r) {
        int row = m0 + wm + mi * 16 + quad * 4 + r;
        C[(size_t)row * NN + col] = acc[mi][ni][r] + bv;
      }
  }
}

// ---------------- flash attention v6: 32x32 MFMA, 128-q blocks, XOR-swizzled LDS ----
// Block = (b,h,128 q-rows): 4 waves x 32 q-rows, shared 64-key K/V tiles (32 iters).
// blockIdx = qb*32 + bh (XCD swizzle; v5-verified FETCH cut).
// Kl row r holds ORIG key tau(r)=2*(r&31)+(r>>5) so P packs bf16x2 and stored-key
// order matches Vt (position j = orig key j). All LDS XOR-swizzled (pitch 64,
// 16B chunk index ^= row&7): staging writes, kf/vf/pf b128 reads, P/V b32 writes
// all conflict-free by mod-32 arithmetic. l accumulated via ones-MFMA per wave:
// no cross-lane, no cross-wave reduce (each wave owns its q-rows). 2 barriers/iter.
__global__ __launch_bounds__(256) void flash_attn(const bf16* __restrict__ Qm,
                                                  const bf16* __restrict__ Km,
                                                  const bf16* __restrict__ Vm,
                                                  bf16* __restrict__ Om)
{
  __shared__ bf16 Kl[64 * 64];      // 8 KB, [stored key][dh], XOR-swizzled
  __shared__ bf16 Vt[64 * 64];      // 8 KB, [dh][stored key], XOR-swizzled
  __shared__ bf16 Pl[4][32 * 64];   // 16 KB, per-wave [q][stored key], XOR-swizzled

  const int tid = threadIdx.x;
  const int w = tid >> 6, L = tid & 63;
  const int l32 = L & 31, hi = L >> 5;
  const int bh = blockIdx.x & 31;
  const int qb = blockIdx.x >> 5;
  const int b = bh >> 4, h = bh & 15;
  const int s0 = qb << 7;                       // 128 q-rows per block
  const size_t base = (size_t)b * 2097152 + h * 64;

  // Q fragments: A[m=l32][k = s*16 + hi*8 + j], scale*log2e folded in
  bf16x8 qf[4];
  const float SL = 0.03125f * 1.44269504088896f;
  {
    const bf16* qp = Qm + base + (size_t)(s0 + w * 32 + l32) * 1024 + hi * 8;
#pragma unroll
    for (int s = 0; s < 4; ++s) {
      bf16x8 tq = *(const bf16x8*)(qp + s * 16);
#pragma unroll
      for (int j = 0; j < 8; ++j) tq[j] = (bf16)((float)tq[j] * SL);
      qf[s] = tq;
    }
  }

  bf16x8 onesf;
#pragma unroll
  for (int j = 0; j < 8; ++j) onesf[j] = (bf16)1.0f;

  f32x16 oacc0 = {}, oacc1 = {}, lacc = {};

  // K staging: lane L fills Kl row L <- orig key 2*l32+hi, dh chunk [w*16, w*16+16)
  const bf16* Kg = Km + base + (size_t)(2 * l32 + hi) * 1024 + w * 16;
  // V staging: lane L loads orig keys 2*l32, 2*l32+1 at dh slice dh8 = w*16+hi*8
  const int dh8 = w * 16 + hi * 8;
  const bf16* Vg = Vm + base + (size_t)(2 * l32) * 1024 + dh8;
  bf16* Pw = &Pl[w][0];
  const int r7 = l32 & 7;                       // row&7 for rows indexed by l32

  bf16x8 k0 = *(const bf16x8*)Kg;
  bf16x8 k1 = *(const bf16x8*)(Kg + 8);
  bf16x8 va = *(const bf16x8*)Vg;
  bf16x8 vb = *(const bf16x8*)(Vg + 1024);

  for (int kt = 0; kt < 32; ++kt) {
    __syncthreads();  // all waves done reading Kl/Vt from prev iter
    // K: row L, chunks 2w, 2w+1 (XOR row&7)
    *(bf16x8*)(Kl + L * 64 + ((((2 * w + 0) ^ (L & 7)) << 3))) = k0;
    *(bf16x8*)(Kl + L * 64 + ((((2 * w + 1) ^ (L & 7)) << 3))) = k1;
    // V transpose: row dh8+j, col pair 2*l32 (b32, conflict-free)
#pragma unroll
    for (int j = 0; j < 8; ++j) {
      int row = dh8 + j;
      bf16x2 pr; pr.x = va[j]; pr.y = vb[j];
      *(bf16x2*)(Vt + row * 64 + (((l32 >> 2) ^ (row & 7)) << 3) + ((l32 & 3) << 1)) = pr;
    }
    if (kt + 1 < 32) {  // register prefetch (in flight during compute)
      k0 = *(const bf16x8*)(Kg + (size_t)(kt + 1) * 65536);
      k1 = *(const bf16x8*)(Kg + (size_t)(kt + 1) * 65536 + 8);
      va = *(const bf16x8*)(Vg + (size_t)(kt + 1) * 65536);
      vb = *(const bf16x8*)(Vg + (size_t)(kt + 1) * 65536 + 1024);
    }
    __syncthreads();  // staged K/V visible

    // S = Q K^T: 32 q x 64 stored keys (2 n-tiles x 4 k-steps)
    f32x16 sa = {}, sb = {};
#pragma unroll
    for (int s = 0; s < 4; ++s) {
      bf16x8 kfa = *(const bf16x8*)(Kl + (l32)      * 64 + (((2 * s + hi) ^ r7) << 3));
      bf16x8 kfb = *(const bf16x8*)(Kl + (32 + l32) * 64 + (((2 * s + hi) ^ r7) << 3));
      sa = __builtin_amdgcn_mfma_f32_32x32x16_bf16(qf[s], kfa, sa, 0, 0, 0);
      sb = __builtin_amdgcn_mfma_f32_32x32x16_bf16(qf[s], kfb, sb, 0, 0, 0);
    }

    // exp2 + packed P store: C row = (reg&3)+8*(reg>>2)+4*hi, cols 2*l32+{0,1}
#pragma unroll
    for (int reg = 0; reg < 16; ++reg) {
      int row = (reg & 3) + ((reg >> 2) << 3) + (hi << 2);
      float p0 = __builtin_amdgcn_exp2f(sa[reg]);
      float p1 = __builtin_amdgcn_exp2f(sb[reg]);
      bf16x2 pv; pv.x = (bf16)p0; pv.y = (bf16)p1;
      *(bf16x2*)(Pw + row * 64 + (((l32 >> 2) ^ (row & 7)) << 3) + ((l32 & 3) << 1)) = pv;
    }
    asm volatile("s_waitcnt lgkmcnt(0)" ::: "memory");  // Pl is wave-local

    // O += P V^T; l += P ones
#pragma unroll
    for (int s = 0; s < 4; ++s) {
      bf16x8 paf = *(const bf16x8*)(Pw + l32 * 64 + (((2 * s + hi) ^ r7) << 3));
      bf16x8 vf0 = *(const bf16x8*)(Vt + (l32)      * 64 + (((2 * s + hi) ^ r7) << 3));
      bf16x8 vf1 = *(const bf16x8*)(Vt + (32 + l32) * 64 + (((2 * s + hi) ^ r7) << 3));
      oacc0 = __builtin_amdgcn_mfma_f32_32x32x16_bf16(paf, vf0, oacc0, 0, 0, 0);
      oacc1 = __builtin_amdgcn_mfma_f32_32x32x16_bf16(paf, vf1, oacc1, 0, 0, 0);
      lacc  = __builtin_amdgcn_mfma_f32_32x32x16_bf16(paf, onesf, lacc, 0, 0, 0);
    }
  }

  // ---- epilogue: every lane holds l for its 16 C-rows in lacc (all cols equal) ----
#pragma unroll
  for (int reg = 0; reg < 16; ++reg) {
    int row = (reg & 3) + ((reg >> 2) << 3) + (hi << 2);
    float inv = 1.f / lacc[reg];
    bf16* op = Om + base + (size_t)(s0 + w * 32 + row) * 1024;
    op[l32]      = (bf16)(oacc0[reg] * inv);
    op[32 + l32] = (bf16)(oacc1[reg] * inv);
  }
}

extern "C" void kernel_launch(void* const* d_in, const int* in_sizes, int n_in,
                              void* d_out, int out_size, void* d_ws, size_t ws_size,
                              hipStream_t stream)
{
  const float* q  = (const float*)d_in[0];
  const float* k  = (const float*)d_in[1];
  const float* v  = (const float*)d_in[2];
  const float* Wq = (const float*)d_in[3];
  const float* bq = (const float*)d_in[4];
  const float* Wk = (const float*)d_in[5];
  const float* bk = (const float*)d_in[6];
  const float* Wv = (const float*)d_in[7];
  const float* bv = (const float*)d_in[8];
  const float* Wo = (const float*)d_in[9];
  const float* bo = (const float*)d_in[10];

  char* ws = (char*)d_ws;
  bf16* Xb  = (bf16*)ws;                    // 3 x 4096x1024 bf16 (dead after gemm_proj)
  bf16* Wt  = (bf16*)(ws + 25165824);       // 3 x 1024x1024 bf16
  bf16* Wot = (bf16*)(ws + 31457280);       // 1024x1024 bf16
  bf16* QKV = (bf16*)(ws + 33554432);       // 3 x 4096x1024 bf16
  bf16* O   = (bf16*)ws;                    // aliases Xb

  cvt_all<<<dim3(13312), 256, 0, stream>>>(q, k, v, Wq, Wk, Wv, Wo, Xb, Wt, Wot);
  gemm_proj<<<dim3(256, 3), 256, 0, stream>>>(Xb, Wt, bq, bk, bv, QKV);
  flash_attn<<<dim3(512), 256, 0, stream>>>(QKV, QKV + 4194304, QKV + 8388608, O);
  gemm_outp<<<dim3(512), 256, 0, stream>>>(O, Wot, bo, (float*)d_out);
}